// Round 18
// baseline (310.223 us; speedup 1.0000x reference)
//
#include <hip/hip_runtime.h>
#include <hip/hip_bf16.h>

#define D_IN 128
#define SORT_CHUNK 4096
#define NBUCK 256

#if __has_builtin(__builtin_amdgcn_cvt_pk_f32_fp8) && __has_builtin(__builtin_amdgcn_cvt_pk_fp8_f32)
#define HAVE_FP8 1
#else
#define HAVE_FP8 0
#endif

typedef __attribute__((ext_vector_type(8))) short bf16x8;
typedef __attribute__((ext_vector_type(8))) unsigned short u16x8;
typedef __attribute__((ext_vector_type(4))) float f32x4;

// ======================= generic exclusive scan (1024/block) =======================

__global__ __launch_bounds__(256) void scan_block_sums(const int* __restrict__ in,
                                                       int* __restrict__ partial,
                                                       int M) {
    __shared__ int sdata[256];
    int b = blockIdx.x, t = threadIdx.x;
    int base = b * 1024 + t * 4;
    int s = 0;
#pragma unroll
    for (int i = 0; i < 4; ++i) {
        int idx = base + i;
        if (idx < M) s += in[idx];
    }
    sdata[t] = s;
    __syncthreads();
    for (int off = 128; off > 0; off >>= 1) {
        if (t < off) sdata[t] += sdata[t + off];
        __syncthreads();
    }
    if (t == 0) partial[b] = sdata[0];
}

// parallel exclusive scan of up to 1024 partials (single block, 256 thr x 4)
__global__ __launch_bounds__(256) void scan_partials(int* __restrict__ partial, int nb) {
    __shared__ int sdata[256];
    int t = threadIdx.x;
    int v[4];
    int s = 0;
#pragma unroll
    for (int i = 0; i < 4; ++i) {
        int idx = t * 4 + i;
        v[i] = (idx < nb) ? partial[idx] : 0;
        s += v[i];
    }
    sdata[t] = s;
    __syncthreads();
    for (int o = 1; o < 256; o <<= 1) {
        int tmp = (t >= o) ? sdata[t - o] : 0;
        __syncthreads();
        sdata[t] += tmp;
        __syncthreads();
    }
    int run = sdata[t] - s;
#pragma unroll
    for (int i = 0; i < 4; ++i) {
        int idx = t * 4 + i;
        if (idx < nb) partial[idx] = run;
        run += v[i];
    }
}

__global__ __launch_bounds__(256) void scan_final(const int* __restrict__ in,
                                                  const int* __restrict__ partial,
                                                  int* __restrict__ outS,
                                                  int M) {
    __shared__ int sdata[256];
    int b = blockIdx.x, t = threadIdx.x;
    int base = b * 1024 + t * 4;
    int v[4];
    int s = 0;
#pragma unroll
    for (int i = 0; i < 4; ++i) {
        int idx = base + i;
        v[i] = (idx < M) ? in[idx] : 0;
        s += v[i];
    }
    sdata[t] = s;
    __syncthreads();
    for (int o = 1; o < 256; o <<= 1) {
        int tmp = 0;
        if (t >= o) tmp = sdata[t - o];
        __syncthreads();
        sdata[t] += tmp;
        __syncthreads();
    }
    int run = partial[b] + (sdata[t] - s);
#pragma unroll
    for (int i = 0; i < 4; ++i) {
        int idx = base + i;
        if (idx < M) outS[idx] = run;
        run += v[i];
    }
}

// ======================= two-pass bucket sort by dst =======================

__global__ __launch_bounds__(256) void bucket_hist_kernel(const int* __restrict__ dst,
                                                          int* __restrict__ bh,
                                                          long long E, int N, int nbe) {
    __shared__ int cnt[NBUCK];
    cnt[threadIdx.x] = 0;
    __syncthreads();
    long long base = (long long)blockIdx.x * SORT_CHUNK;
    long long end = base + SORT_CHUNK;
    if (end > E) end = E;
    for (long long i = base + threadIdx.x; i < end; i += 256) {
        int b = (int)(((long long)dst[i] << 8) / N);
        atomicAdd(&cnt[b], 1);
    }
    __syncthreads();
    bh[threadIdx.x * nbe + blockIdx.x] = cnt[threadIdx.x];
}

__global__ __launch_bounds__(256) void bucket_scatter_kernel(const int* __restrict__ src,
                                                             const int* __restrict__ dst,
                                                             const float* __restrict__ ew,
                                                             const int* __restrict__ S,
                                                             int2* __restrict__ tmp_edges,
                                                             int* __restrict__ tmp_dst,
                                                             long long E, int N, int nbe) {
    __shared__ int base_lds[NBUCK];
    __shared__ int cnt[NBUCK];
    base_lds[threadIdx.x] = S[threadIdx.x * nbe + blockIdx.x];
    cnt[threadIdx.x] = 0;
    __syncthreads();
    long long b0 = (long long)blockIdx.x * SORT_CHUNK;
    long long e1 = b0 + SORT_CHUNK;
    if (e1 > E) e1 = E;
    for (long long i = b0 + threadIdx.x; i < e1; i += 256) {
        int d = dst[i];
        int b = (int)(((long long)d << 8) / N);
        int p = base_lds[b] + atomicAdd(&cnt[b], 1);
        tmp_edges[p] = make_int2(src[i], __float_as_int(ew[i]));
        tmp_dst[p] = d;
    }
}

__global__ __launch_bounds__(256) void bucket_sort_kernel(const int* __restrict__ S,
                                                          const int2* __restrict__ tmp_edges,
                                                          const int* __restrict__ tmp_dst,
                                                          int2* __restrict__ edges,
                                                          int* __restrict__ hist,
                                                          int* __restrict__ off,
                                                          long long E, int N, int nbe) {
    __shared__ int cnt[512];
    __shared__ int tsum[256];
    __shared__ int pos[512];
    const int b = blockIdx.x, t = threadIdx.x;
    const int lo = (int)(((long long)b * N + 255) >> 8);
    const int hi = (int)(((long long)(b + 1) * N + 255) >> 8);
    const int start = S[b * nbe];
    const int end = (b == NBUCK - 1) ? (int)E : S[(b + 1) * nbe];

    cnt[t] = 0;
    cnt[t + 256] = 0;
    __syncthreads();
    for (int i = start + t; i < end; i += 256)
        atomicAdd(&cnt[tmp_dst[i] - lo], 1);
    __syncthreads();

    int a0 = cnt[2 * t], a1 = cnt[2 * t + 1];
    tsum[t] = a0 + a1;
    __syncthreads();
    for (int o = 1; o < 256; o <<= 1) {
        int v = (t >= o) ? tsum[t - o] : 0;
        __syncthreads();
        tsum[t] += v;
        __syncthreads();
    }
    int excl = tsum[t] - (a0 + a1);
    pos[2 * t]     = start + excl;
    pos[2 * t + 1] = start + excl + a0;

    int d0 = lo + 2 * t, d1 = lo + 2 * t + 1;
    if (d0 < hi) { hist[d0] = a0; off[d0] = start + excl + a0; }
    if (d1 < hi) { hist[d1] = a1; off[d1] = start + excl + a0 + a1; }
    __syncthreads();

    for (int i = start + t; i < end; i += 256) {
        int d = tmp_dst[i] - lo;
        int r = atomicAdd(&pos[d], 1);
        edges[r] = tmp_edges[i];
    }
}

// ======================= dtype conversions =======================

// x (f32) -> xb (bf16) and x8 (fp8 e4m3, packed 4/u32)
__global__ __launch_bounds__(256) void conv_x_kernel(const float* __restrict__ x,
                                                     __hip_bfloat16* __restrict__ xb,
                                                     unsigned int* __restrict__ x8,
                                                     long long total4) {
    long long i = (long long)blockIdx.x * 256 + threadIdx.x;
    if (i >= total4) return;
    float4 v = reinterpret_cast<const float4*>(x)[i];
    union { ushort4 u; __hip_bfloat162 h2[2]; } o;
    o.h2[0] = __float22bfloat162_rn(make_float2(v.x, v.y));
    o.h2[1] = __float22bfloat162_rn(make_float2(v.z, v.w));
    reinterpret_cast<ushort4*>(xb)[i] = o.u;
#if HAVE_FP8
    int p = 0;
    p = __builtin_amdgcn_cvt_pk_fp8_f32(v.x, v.y, p, false);
    p = __builtin_amdgcn_cvt_pk_fp8_f32(v.z, v.w, p, true);
    x8[i] = (unsigned int)p;
#endif
}

#if HAVE_FP8
// hb (bf16) -> h8 (fp8)
__global__ __launch_bounds__(256) void conv_h8_kernel(const __hip_bfloat16* __restrict__ hb,
                                                      unsigned int* __restrict__ h8,
                                                      long long total4) {
    long long i = (long long)blockIdx.x * 256 + threadIdx.x;
    if (i >= total4) return;
    ushort4 v = reinterpret_cast<const ushort4*>(hb)[i];
    float f0 = __int_as_float((unsigned)v.x << 16);
    float f1 = __int_as_float((unsigned)v.y << 16);
    float f2 = __int_as_float((unsigned)v.z << 16);
    float f3 = __int_as_float((unsigned)v.w << 16);
    int p = 0;
    p = __builtin_amdgcn_cvt_pk_fp8_f32(f0, f1, p, false);
    p = __builtin_amdgcn_cvt_pk_fp8_f32(f2, f3, p, true);
    h8[i] = (unsigned int)p;
}
#endif

// K-chunk-major weights, per 64-col strip (proven conflict-free):
//   chunk s = kc*64 + col (kc 0..31, K=256 = [Wrel;Wroot]),
//   Wt[strip][s*8 + j] = W[kc*8+j][strip*64+col]
template <int DOUT>
__global__ __launch_bounds__(256) void conv_w_kernel(const float* __restrict__ Wrel,
                                                     const float* __restrict__ Wroot,
                                                     __hip_bfloat16* __restrict__ Wt) {
    int idx = blockIdx.x * 256 + threadIdx.x;
    if (idx >= DOUT * 256) return;
    int strip  = idx >> 14;
    int within = idx & 16383;
    int s      = within >> 3;
    int j      = within & 7;
    int kchunk = s >> 6;
    int col    = s & 63;
    int k      = kchunk * 8 + j;
    int jcol   = strip * 64 + col;
    float v = (k < 128) ? Wrel[(size_t)k * DOUT + jcol]
                        : Wroot[(size_t)(k - 128) * DOUT + jcol];
    Wt[idx] = __float2bfloat16(v);
}

// =============== segmented aggregation: fp8 gather (8B/lane), f32 accum, bf16 out ===============
#if HAVE_FP8
__global__ __launch_bounds__(256) void aggregate_fp8_kernel(const unsigned char* __restrict__ feat8,
                                                            const int2* __restrict__ edges,
                                                            const int* __restrict__ off,
                                                            const int* __restrict__ hist,
                                                            __hip_bfloat16* __restrict__ aggb,
                                                            int N) {
    int node = blockIdx.x * 4 + (threadIdx.x >> 6);
    if (node >= N) return;
    const int lane = threadIdx.x & 63;
    const int g = lane >> 4;        // edge slot 0..3
    const int sub = lane & 15;      // 8-elem chunk
    const int cnt = hist[node];
    const int end = off[node];
    const int start = end - cnt;
    const float inv = 1.0f / fmaxf((float)cnt, 1.0f);

    const uint2* fb = (const uint2*)feat8;   // 16 x uint2 per 128-elem row
    float acc[8] = {0.f, 0.f, 0.f, 0.f, 0.f, 0.f, 0.f, 0.f};

#define ACCUM(RW, W)                                                          \
    {                                                                         \
        auto p0 = __builtin_amdgcn_cvt_pk_f32_fp8((RW).x, false);             \
        auto p1 = __builtin_amdgcn_cvt_pk_f32_fp8((RW).x, true);              \
        auto p2 = __builtin_amdgcn_cvt_pk_f32_fp8((RW).y, false);             \
        auto p3 = __builtin_amdgcn_cvt_pk_f32_fp8((RW).y, true);              \
        acc[0] += (W) * p0[0]; acc[1] += (W) * p0[1];                         \
        acc[2] += (W) * p1[0]; acc[3] += (W) * p1[1];                         \
        acc[4] += (W) * p2[0]; acc[5] += (W) * p2[1];                         \
        acc[6] += (W) * p3[0]; acc[7] += (W) * p3[1];                         \
    }

    int e = start + g;
    for (; e + 4 < end; e += 8) {
        int2 e0 = edges[e];
        int2 e1 = edges[e + 4];
        float w0 = __int_as_float(e0.y);
        float w1 = __int_as_float(e1.y);
        uint2 r0 = fb[(size_t)e0.x * 16 + sub];
        uint2 r1 = fb[(size_t)e1.x * 16 + sub];
        ACCUM(r0, w0)
        ACCUM(r1, w1)
    }
    if (e < end) {
        int2 e0 = edges[e];
        float w0 = __int_as_float(e0.y);
        uint2 r0 = fb[(size_t)e0.x * 16 + sub];
        ACCUM(r0, w0)
    }
#undef ACCUM

#pragma unroll
    for (int j = 0; j < 8; ++j) {
        acc[j] += __shfl_xor(acc[j], 16, 64);
        acc[j] += __shfl_xor(acc[j], 32, 64);
    }

    if (g == 0) {
        union { u16x8 u; __hip_bfloat162 h2[4]; } o;
#pragma unroll
        for (int j = 0; j < 4; ++j)
            o.h2[j] = __float22bfloat162_rn(make_float2(acc[2 * j] * inv, acc[2 * j + 1] * inv));
        *reinterpret_cast<u16x8*>((ushort*)aggb + (size_t)node * 128 + sub * 8) = o.u;
    }
}
#endif

// =============== bf16 aggregation (fallback path) ===============
__global__ __launch_bounds__(256) void aggregate_kernel(const __hip_bfloat16* __restrict__ featb,
                                                        const int2* __restrict__ edges,
                                                        const int* __restrict__ off,
                                                        const int* __restrict__ hist,
                                                        __hip_bfloat16* __restrict__ aggb,
                                                        int N) {
    int node = blockIdx.x * 4 + (threadIdx.x >> 6);
    if (node >= N) return;
    const int lane = threadIdx.x & 63;
    const int g = lane >> 4;
    const int sub = lane & 15;
    const int cnt = hist[node];
    const int end = off[node];
    const int start = end - cnt;
    const float inv = 1.0f / fmaxf((float)cnt, 1.0f);

    const ushort* fb = (const ushort*)featb;
    float acc[8] = {0.f, 0.f, 0.f, 0.f, 0.f, 0.f, 0.f, 0.f};

    int e = start + g;
    for (; e + 4 < end; e += 8) {
        int2 e0 = edges[e];
        int2 e1 = edges[e + 4];
        float w0 = __int_as_float(e0.y);
        float w1 = __int_as_float(e1.y);
        u16x8 r0 = *reinterpret_cast<const u16x8*>(fb + (size_t)e0.x * 128 + sub * 8);
        u16x8 r1 = *reinterpret_cast<const u16x8*>(fb + (size_t)e1.x * 128 + sub * 8);
#pragma unroll
        for (int j = 0; j < 8; ++j) {
            acc[j] += w0 * __int_as_float((unsigned)r0[j] << 16)
                    + w1 * __int_as_float((unsigned)r1[j] << 16);
        }
    }
    if (e < end) {
        int2 e0 = edges[e];
        float w0 = __int_as_float(e0.y);
        u16x8 r0 = *reinterpret_cast<const u16x8*>(fb + (size_t)e0.x * 128 + sub * 8);
#pragma unroll
        for (int j = 0; j < 8; ++j)
            acc[j] += w0 * __int_as_float((unsigned)r0[j] << 16);
    }

#pragma unroll
    for (int j = 0; j < 8; ++j) {
        acc[j] += __shfl_xor(acc[j], 16, 64);
        acc[j] += __shfl_xor(acc[j], 32, 64);
    }

    if (g == 0) {
        union { u16x8 u; __hip_bfloat162 h2[4]; } o;
#pragma unroll
        for (int j = 0; j < 4; ++j)
            o.h2[j] = __float22bfloat162_rn(make_float2(acc[2 * j] * inv, acc[2 * j + 1] * inv));
        *reinterpret_cast<u16x8*>((ushort*)aggb + (size_t)node * 128 + sub * 8) = o.u;
    }
}

// =============== MFMA GEMM v7: B-resident persistent blocks, dbuf A panels ===============
template <int DOUT, bool OUT_BF16>
__global__ __launch_bounds__(256, 2) void gemm_mfma7(const __hip_bfloat16* __restrict__ Arel,
                                                     const __hip_bfloat16* __restrict__ Aroot,
                                                     const __hip_bfloat16* __restrict__ Wt,
                                                     const float* __restrict__ bias,
                                                     void* __restrict__ outp,
                                                     int M, int per_strip, int ppb) {
    __shared__ __align__(16) unsigned char Bs[32768];
    __shared__ __align__(16) unsigned char As[2][16384];

    const int nb = gridDim.x;
    const int orig = blockIdx.x;
    const int xcd = orig & 7;
    const int lid0 = orig >> 3;
    const int q = nb >> 3, r = nb & 7;
    const int wgid = (xcd < r ? xcd * (q + 1) : r * (q + 1) + (xcd - r) * q) + lid0;

    const int ty = wgid / per_strip;
    const int lid = wgid % per_strip;
    const int npan = (M + 31) >> 5;
    const int p0 = lid * ppb;
    const int pend = min(p0 + ppb, npan);

    const int tid = threadIdx.x;
    const int lane = tid & 63;
    const int wave = tid >> 6;
    const int lr = lane & 15;
    const int lk = lane >> 4;
    const int wr = wave >> 1;
    const int wc = wave & 1;

    const char* wbase = (const char*)Wt + (size_t)ty * 32768;
#pragma unroll
    for (int i = 0; i < 8; ++i) {
        int s = i * 256 + tid;
        __builtin_amdgcn_global_load_lds(
            (const __attribute__((address_space(1))) unsigned int*)(wbase + (size_t)s * 16),
            (__attribute__((address_space(3))) unsigned int*)(&Bs[s * 16]),
            16, 0, 0);
    }

    auto stageA = [&](int panel, int buf) {
#pragma unroll
        for (int i = 0; i < 4; ++i) {
            int s = i * 256 + tid;
            int kc = s >> 5;
            int rloc = s & 31;
            int row = panel * 32 + rloc;
            int rc = row < M ? row : M - 1;
            const short* srcp = (kc < 16)
                ? (const short*)Arel  + (size_t)rc * 128 + kc * 8
                : (const short*)Aroot + (size_t)rc * 128 + (kc - 16) * 8;
            __builtin_amdgcn_global_load_lds(
                (const __attribute__((address_space(1))) unsigned int*)srcp,
                (__attribute__((address_space(3))) unsigned int*)(&As[buf][s * 16]),
                16, 0, 0);
        }
    };

    if (p0 < pend) stageA(p0, 0);
    __syncthreads();

    f32x4 zero = {0.f, 0.f, 0.f, 0.f};

    for (int p = p0; p < pend; ++p) {
        const int cur = (p - p0) & 1;
        if (p + 1 < pend) stageA(p + 1, cur ^ 1);

        f32x4 acc0 = zero, acc1 = zero;
#pragma unroll
        for (int kk = 0; kk < 8; ++kk) {
            const int chunk = kk * 4 + lk;
            bf16x8 a  = *reinterpret_cast<const bf16x8*>(&As[cur][(chunk * 32 + wr * 16 + lr) * 16]);
            bf16x8 b0 = *reinterpret_cast<const bf16x8*>(&Bs[(chunk * 64 + wc * 32 + lr) * 16]);
            bf16x8 b1 = *reinterpret_cast<const bf16x8*>(&Bs[(chunk * 64 + wc * 32 + 16 + lr) * 16]);
            acc0 = __builtin_amdgcn_mfma_f32_16x16x32_bf16(a, b0, acc0, 0, 0, 0);
            acc1 = __builtin_amdgcn_mfma_f32_16x16x32_bf16(a, b1, acc1, 0, 0, 0);
        }

#pragma unroll
        for (int ni = 0; ni < 2; ++ni) {
            int col = ty * 64 + wc * 32 + ni * 16 + lr;
            float bv = bias[col];
            const f32x4& av = ni ? acc1 : acc0;
#pragma unroll
            for (int rr = 0; rr < 4; ++rr) {
                int row = p * 32 + wr * 16 + lk * 4 + rr;
                if (row < M) {
                    float v = av[rr] + bv;
                    if (OUT_BF16)
                        ((__hip_bfloat16*)outp)[(size_t)row * DOUT + col] = __float2bfloat16(v);
                    else
                        ((float*)outp)[(size_t)row * DOUT + col] = v;
                }
            }
        }
        __syncthreads();
    }
}

// ======================= launch =======================

extern "C" void kernel_launch(void* const* d_in, const int* in_sizes, int n_in,
                              void* d_out, int out_size, void* d_ws, size_t ws_size,
                              hipStream_t stream) {
    const float* x      = (const float*)d_in[0];
    const int*   ei     = (const int*)d_in[1];
    const float* ew     = (const float*)d_in[2];
    const float* Wrel1  = (const float*)d_in[3];
    const float* b1     = (const float*)d_in[4];
    const float* Wroot1 = (const float*)d_in[5];
    const float* Wrel2  = (const float*)d_in[6];
    const float* b2     = (const float*)d_in[7];
    const float* Wroot2 = (const float*)d_in[8];
    float* out = (float*)d_out;

    const int N = in_sizes[0] / D_IN;
    const long long E = in_sizes[2];
    const int* src = ei;
    const int* dst = ei + E;

    const int nbe = (int)((E + SORT_CHUNK - 1) / SORT_CHUNK);
    const int M = nbe * NBUCK;
    const int nbM = (M + 1023) / 1024;

    int* hist = (int*)d_ws;
    int* off  = hist + N;
    int* part = off + N;
    int2* edges = (int2*)(part + 1024);
    __hip_bfloat16* agg1b = (__hip_bfloat16*)(edges + E);
    __hip_bfloat16* xb    = agg1b + (size_t)N * D_IN;
    __hip_bfloat16* agg2b = xb    + (size_t)N * D_IN;
    __hip_bfloat16* hb    = agg2b + (size_t)N * D_IN;
    __hip_bfloat16* Wt1   = hb    + (size_t)N * D_IN;
    __hip_bfloat16* Wt2   = Wt1   + 128 * 256;

    // transient sort buffers overlapped into agg regions (consumed before aggregates run)
    int* bh      = (int*)agg1b;
    int* S       = bh + M;
    int* tmp_dst = S + M;
    int2* tmp_edges = (int2*)agg2b;

    // fp8 tables overlap dead windows:
    //   x8 in agg2b region (tmp_edges consumed before conv; agg2b written after agg1 reads x8... 
    //   actually agg2b is written by aggregate #2 which runs after x8 is dead)
    //   h8 in agg1b region (agg1b dead after gemm1)
    unsigned int* x8 = (unsigned int*)agg2b;
    unsigned int* h8 = (unsigned int*)agg1b;

    // ---- sort edges by dst ----
    bucket_hist_kernel<<<nbe, 256, 0, stream>>>(dst, bh, E, N, nbe);
    scan_block_sums<<<nbM, 256, 0, stream>>>(bh, part, M);
    scan_partials<<<1, 256, 0, stream>>>(part, nbM);
    scan_final<<<nbM, 256, 0, stream>>>(bh, part, S, M);
    bucket_scatter_kernel<<<nbe, 256, 0, stream>>>(src, dst, ew, S, tmp_edges, tmp_dst, E, N, nbe);
    bucket_sort_kernel<<<NBUCK, 256, 0, stream>>>(S, tmp_edges, tmp_dst, edges, hist, off, E, N, nbe);

    // ---- conversions (after sort: x8 overlaps tmp_edges region, now dead) ----
    {
        long long total4 = (long long)N * D_IN / 4;
        conv_x_kernel<<<(int)((total4 + 255) / 256), 256, 0, stream>>>(x, xb, x8, total4);
        conv_w_kernel<128><<<(128 * 256 + 255) / 256, 256, 0, stream>>>(Wrel1, Wroot1, Wt1);
        conv_w_kernel<256><<<(256 * 256 + 255) / 256, 256, 0, stream>>>(Wrel2, Wroot2, Wt2);
    }

    const int ab = (N + 3) / 4;
    const int npan = (N + 31) >> 5;
    const long long total4 = (long long)N * D_IN / 4;

    // ---- layer 1 ----
#if HAVE_FP8
    aggregate_fp8_kernel<<<ab, 256, 0, stream>>>((const unsigned char*)x8, edges, off, hist, agg1b, N);
#else
    aggregate_kernel<<<ab, 256, 0, stream>>>(xb, edges, off, hist, agg1b, N);
#endif
    {
        int per_strip = 256;
        int ppb = (npan + per_strip - 1) / per_strip;
        gemm_mfma7<128, true><<<2 * per_strip, 256, 0, stream>>>(agg1b, xb, Wt1, b1, hb, N, per_strip, ppb);
    }

    // ---- layer 2 ----
#if HAVE_FP8
    conv_h8_kernel<<<(int)((total4 + 255) / 256), 256, 0, stream>>>(hb, h8, total4);
    aggregate_fp8_kernel<<<ab, 256, 0, stream>>>((const unsigned char*)h8, edges, off, hist, agg2b, N);
#else
    aggregate_kernel<<<ab, 256, 0, stream>>>(hb, edges, off, hist, agg2b, N);
#endif
    {
        int per_strip = 256;
        int ppb = (npan + per_strip - 1) / per_strip;
        gemm_mfma7<256, false><<<4 * per_strip, 256, 0, stream>>>(agg2b, hb, Wt2, b2, out, N, per_strip, ppb);
    }
}